// Round 9
// baseline (718.928 us; speedup 1.0000x reference)
//
#include <hip/hip_runtime.h>
#include <hip/hip_cooperative_groups.h>
#include <math.h>

namespace cg = cooperative_groups;

#define TYPE_N 5
#define D 256
#define EPS 1e-6f
#define NCOPY 16

// ws layout (float offsets):
//   [0, 20480)        sums_partial[NCOPY][TYPE_N][D]
//   [20480, 20560)    counts_partial[NCOPY][TYPE_N]
//   [20560, 21840)    center[TYPE_N][D]          (raw)
//   [21840, 21845)    counts_final[TYPE_N]
//   [21845, 21925)    dsum_partial[NCOPY][TYPE_N]
//   [21925, 23205)    cme[TYPE_N][D]             (center - EPS)
#define OFF_CNTP   (NCOPY * TYPE_N * D)          // 20480
#define OFF_CENTER (OFF_CNTP + NCOPY * TYPE_N)   // 20560
#define OFF_CNTF   (OFF_CENTER + TYPE_N * D)     // 21840
#define OFF_DSUM   (OFF_CNTF + TYPE_N)           // 21845
#define OFF_CME    (OFF_DSUM + NCOPY * TYPE_N)   // 21925
#define WS_FLOATS  (OFF_CME + TYPE_N * D)        // 23205

__device__ __forceinline__ int argmax5(const float* __restrict__ yr) {
    int lab = 0;
    float best = yr[0];
    #pragma unroll
    for (int c = 1; c < TYPE_N; ++c) {
        float v = yr[c];
        if (v > best) { best = v; lab = c; }
    }
    return lab;
}

// serial lane-0 label + broadcast — part of the PROVEN-fast R0 k1 loop shape.
__device__ __forceinline__ int row_label(const float* __restrict__ y, int r, int lane) {
    int lab = 0;
    if (lane == 0) {
        const float* yr = y + (size_t)r * TYPE_N;
        float best = yr[0];
        #pragma unroll
        for (int c = 1; c < TYPE_N; ++c) {
            float v = yr[c];
            if (v > best) { best = v; lab = c; }
        }
    }
    return __shfl(lab, 0);
}

// Fused k1+k2+k3+k4 with grid-wide syncs. Phase bodies are byte-identical to
// the measured-best separate kernels (R6: k1~60us, k3~38us). LDS = 20480 B
// exactly -> 8 blocks/CU. NO early returns (cooperative).
__global__ __launch_bounds__(256, 8) void fused(const float* __restrict__ x,
                                                const float* __restrict__ y,
                                                float* __restrict__ ws,
                                                float* __restrict__ out, int N) {
    __shared__ float lsum[4][TYPE_N][D];   // 20480 B exactly
    float* lflat = &lsum[0][0][0];
    cg::grid_group grid = cg::this_grid();
    const int lane = threadIdx.x & 63;
    const int wid  = threadIdx.x >> 6;
    const int t    = threadIdx.x;

    // ================= Phase A: per-class counts + column sums (R0-k1) ======
    {
        float acc[TYPE_N][4] = {};
        float cnt[TYPE_N] = {};
        const float cw = (lane == 0) ? 1.0f : 0.0f;
        const int stride = gridDim.x * 4;
        for (int r = blockIdx.x * 4 + wid; r < N; r += stride) {
            int lab = row_label(y, r, lane);
            const float4 v = *reinterpret_cast<const float4*>(x + (size_t)r * D + lane * 4);
            #pragma unroll
            for (int c = 0; c < TYPE_N; ++c) {
                float m = (lab == c) ? 1.0f : 0.0f;
                acc[c][0] = fmaf(m, v.x, acc[c][0]);
                acc[c][1] = fmaf(m, v.y, acc[c][1]);
                acc[c][2] = fmaf(m, v.z, acc[c][2]);
                acc[c][3] = fmaf(m, v.w, acc[c][3]);
                cnt[c]    = fmaf(m, cw, cnt[c]);
            }
        }
        // counts: stage lane0's per-wave counts through reused LDS
        if (lane == 0) {
            #pragma unroll
            for (int c = 0; c < TYPE_N; ++c) lflat[wid * TYPE_N + c] = cnt[c];
        }
        __syncthreads();
        if (t < TYPE_N) {
            float s = lflat[t] + lflat[TYPE_N + t] + lflat[2 * TYPE_N + t] + lflat[3 * TYPE_N + t];
            atomicAdd(&ws[OFF_CNTP + (blockIdx.x % NCOPY) * TYPE_N + t], s);
        }
        __syncthreads();
        // column sums via LDS reduce of the 4 wave-copies
        #pragma unroll
        for (int c = 0; c < TYPE_N; ++c)
            *reinterpret_cast<float4*>(&lsum[wid][c][lane * 4]) =
                make_float4(acc[c][0], acc[c][1], acc[c][2], acc[c][3]);
        __syncthreads();
        float* sums = ws + (size_t)(blockIdx.x % NCOPY) * (TYPE_N * D);
        #pragma unroll
        for (int c = 0; c < TYPE_N; ++c) {
            float s = lsum[0][c][t] + lsum[1][c][t] + lsum[2][c][t] + lsum[3][c][t];
            atomicAdd(&sums[c * D + t], s);
        }
    }

    __threadfence();
    grid.sync();

    // ================= Phase B: reduce partials -> centers (k2, block 0) ====
    if (blockIdx.x == 0) {
        float cnts[TYPE_N];
        #pragma unroll
        for (int c = 0; c < TYPE_N; ++c) {
            float s = 0.f;
            #pragma unroll
            for (int p = 0; p < NCOPY; ++p) s += ws[OFF_CNTP + p * TYPE_N + c];
            cnts[c] = s;
        }
        float* center = ws + OFF_CENTER;
        float* cme    = ws + OFF_CME;
        #pragma unroll
        for (int c = 0; c < TYPE_N; ++c) {
            float s = 0.f;
            #pragma unroll
            for (int p = 0; p < NCOPY; ++p) s += ws[p * TYPE_N * D + c * D + t];
            float sc = fmaxf(cnts[c], 1.0f);
            float ctr = (cnts[c] > 0.f) ? s / sc : 0.f;
            center[c * D + t] = ctr;
            cme[c * D + t]    = ctr - EPS;
        }
        if (t < TYPE_N) ws[OFF_CNTF + t] = cnts[t];
    }

    __threadfence();
    grid.sync();

    // ================= Phase C: row-per-thread distances (k3) ===============
    {
        float dsloc[TYPE_N] = {};
        const int gsize = gridDim.x * 256;
        for (int r = blockIdx.x * 256 + t; r < N; r += gsize) {
            const int lab = argmax5(y + (size_t)r * TYPE_N);
            const float4* xr = reinterpret_cast<const float4*>(x + (size_t)r * D);
            const float4* cr = reinterpret_cast<const float4*>(ws + OFF_CME + lab * D);
            float ss[4] = {0.f, 0.f, 0.f, 0.f};
            #pragma unroll 8
            for (int i = 0; i < 64; ++i) {
                const float4 a = xr[i];
                const float4 b = cr[i];
                const float t0 = a.x - b.x;
                const float t1 = a.y - b.y;
                const float t2 = a.z - b.z;
                const float t3 = a.w - b.w;
                float s = fmaf(t0, t0, t1 * t1);
                s = fmaf(t2, t2, s);
                s = fmaf(t3, t3, s);
                ss[i & 3] += s;
            }
            const float d = sqrtf(ss[0] + ss[1] + ss[2] + ss[3]);
            #pragma unroll
            for (int c = 0; c < TYPE_N; ++c)
                dsloc[c] += (lab == c) ? d : 0.f;
        }
        #pragma unroll
        for (int c = 0; c < TYPE_N; ++c) {
            float v = dsloc[c];
            #pragma unroll
            for (int off = 32; off > 0; off >>= 1) v += __shfl_xor(v, off);
            if (lane == 0) lflat[wid * TYPE_N + c] = v;
        }
        __syncthreads();
        if (t < TYPE_N) {
            float s = lflat[t] + lflat[TYPE_N + t] + lflat[2 * TYPE_N + t] + lflat[3 * TYPE_N + t];
            atomicAdd(&ws[OFF_DSUM + (blockIdx.x % NCOPY) * TYPE_N + t], s);
        }
    }

    __threadfence();
    grid.sync();

    // ================= Phase D: scalar epilogue (k4, block 0, wave 0) =======
    if (blockIdx.x == 0 && t < 64) {
        const float* center = ws + OFF_CENTER;
        const float* counts = ws + OFF_CNTF;
        const float* dsp    = ws + OFF_DSUM;

        float csum[TYPE_N];
        #pragma unroll
        for (int c = 0; c < TYPE_N; ++c) {
            float s = 0.f;
            #pragma unroll
            for (int k = 0; k < 4; ++k) s += center[c * D + t * 4 + k];
            #pragma unroll
            for (int off = 32; off > 0; off >>= 1) s += __shfl_xor(s, off);
            csum[c] = s;
        }

        float cnts[TYPE_N], dsum[TYPE_N];
        bool present[TYPE_N];
        float real_n = 0.f;
        #pragma unroll
        for (int c = 0; c < TYPE_N; ++c) {
            cnts[c] = counts[c];
            float s = 0.f;
            #pragma unroll
            for (int p = 0; p < NCOPY; ++p) s += dsp[p * TYPE_N + c];
            dsum[c] = s;
            present[c] = (cnts[c] > 0.f) && (csum[c] != 0.f);
            real_n += present[c] ? 1.f : 0.f;
        }

        float loss_pos = 0.f;
        #pragma unroll
        for (int c = 0; c < TYPE_N; ++c) {
            float pcm = dsum[c] / fmaxf(cnts[c], 1.f);
            loss_pos += present[c] ? pcm : 0.f;
        }
        loss_pos = (real_n > 0.f) ? loss_pos / fmaxf(real_n, 1.f) : 1.0f;

        float pairsum = 0.f;
        #pragma unroll
        for (int i = 0; i < TYPE_N; ++i) {
            #pragma unroll
            for (int j = i + 1; j < TYPE_N; ++j) {
                float s = 0.f;
                #pragma unroll
                for (int k = 0; k < 4; ++k) {
                    float dd = center[i * D + t * 4 + k] - center[j * D + t * 4 + k] + EPS;
                    s += dd * dd;
                }
                #pragma unroll
                for (int off = 32; off > 0; off >>= 1) s += __shfl_xor(s, off);
                float pd = sqrtf(s);
                pairsum += (present[i] && present[j]) ? pd : 0.f;
            }
        }
        float n_pairs = real_n * (real_n - 1.f) * 0.5f;
        float loss_neg = (real_n > 1.f) ? pairsum / fmaxf(n_pairs, 1.f) : 0.f;

        if (t == 0) out[0] = loss_pos / (loss_neg + loss_pos);
    }
}

extern "C" void kernel_launch(void* const* d_in, const int* in_sizes, int n_in,
                              void* d_out, int out_size, void* d_ws, size_t ws_size,
                              hipStream_t stream) {
    const float* x = (const float*)d_in[0];
    const float* y = (const float*)d_in[1];
    float* out = (float*)d_out;
    float* ws  = (float*)d_ws;
    int N = in_sizes[0] / D;  // 200000

    (void)hipMemsetAsync(d_ws, 0, (size_t)WS_FLOATS * sizeof(float), stream);

    // co-residency-safe grid size for the cooperative launch
    int nb = 0;
    if (hipOccupancyMaxActiveBlocksPerMultiprocessor(&nb, fused, 256, 0) != hipSuccess || nb < 1)
        nb = 4;
    int dev = 0, numCU = 0;
    (void)hipGetDevice(&dev);
    if (hipDeviceGetAttribute(&numCU, hipDeviceAttributeMultiprocessorCount, dev) != hipSuccess
        || numCU <= 0)
        numCU = 256;
    int grid = nb * numCU;
    if (grid > 2048) grid = 2048;

    void* args[] = {(void*)&x, (void*)&y, (void*)&ws, (void*)&out, (void*)&N};
    (void)hipLaunchCooperativeKernel(fused, dim3(grid), dim3(256), args, 0, stream);
}

// Round 10
// 341.427 us; speedup vs baseline: 2.1057x; 2.1057x over previous
//
#include <hip/hip_runtime.h>
#include <math.h>

#define TYPE_N 5
#define D 256
#define EPS 1e-6f
#define NCOPY 16

// ws layout (float offsets):
//   [0, 20480)        sums_partial[NCOPY][TYPE_N][D]
//   [20480, 20560)    counts_partial[NCOPY][TYPE_N]
//   [20560, 21840)    center[TYPE_N][D]          (raw)
//   [21840, 21845)    counts_final[TYPE_N]
//   [21845, 21925)    dsum_partial[NCOPY][TYPE_N]
//   [21925, 23205)    cme[TYPE_N][D]             (center - EPS)
//   [23205, 23207)    done counters (int): k1, k3
#define OFF_CNTP   (NCOPY * TYPE_N * D)          // 20480
#define OFF_CENTER (OFF_CNTP + NCOPY * TYPE_N)   // 20560
#define OFF_CNTF   (OFF_CENTER + TYPE_N * D)     // 21840
#define OFF_DSUM   (OFF_CNTF + TYPE_N)           // 21845
#define OFF_CME    (OFF_DSUM + NCOPY * TYPE_N)   // 21925
#define OFF_DONE   (OFF_CME + TYPE_N * D)        // 23205
#define WS_FLOATS  (OFF_DONE + 2)                // 23207

__device__ __forceinline__ int argmax5(const float* __restrict__ yr) {
    int lab = 0;
    float best = yr[0];
    #pragma unroll
    for (int c = 1; c < TYPE_N; ++c) {
        float v = yr[c];
        if (v > best) { best = v; lab = c; }
    }
    return lab;
}

// serial lane-0 label + broadcast — part of the PROVEN-fast R0 k1 loop shape.
__device__ __forceinline__ int row_label(const float* __restrict__ y, int r, int lane) {
    int lab = 0;
    if (lane == 0) {
        const float* yr = y + (size_t)r * TYPE_N;
        float best = yr[0];
        #pragma unroll
        for (int c = 1; c < TYPE_N; ++c) {
            float v = yr[c];
            if (v > best) { best = v; lab = c; }
        }
    }
    return __shfl(lab, 0);
}

// --- K1 (+k2 in last block): counts + column sums -> centers -----------------
// Loop body is byte-identical to the measured ~60us R0/R6 k1. Do not touch.
__global__ __launch_bounds__(256) void k1_sums(const float* __restrict__ x,
                                               const float* __restrict__ y,
                                               float* __restrict__ ws, int N) {
    __shared__ float lsum[4][TYPE_N][D];
    __shared__ float lcnt[4][TYPE_N];
    __shared__ int is_last;
    const int lane = threadIdx.x & 63;
    const int wid  = threadIdx.x >> 6;
    float acc[TYPE_N][4] = {};
    float cnt[TYPE_N] = {};
    const float cw = (lane == 0) ? 1.0f : 0.0f;
    const int stride = gridDim.x * 4;
    for (int r = blockIdx.x * 4 + wid; r < N; r += stride) {
        int lab = row_label(y, r, lane);
        const float4 v = *reinterpret_cast<const float4*>(x + (size_t)r * D + lane * 4);
        #pragma unroll
        for (int c = 0; c < TYPE_N; ++c) {
            float m = (lab == c) ? 1.0f : 0.0f;
            acc[c][0] = fmaf(m, v.x, acc[c][0]);
            acc[c][1] = fmaf(m, v.y, acc[c][1]);
            acc[c][2] = fmaf(m, v.z, acc[c][2]);
            acc[c][3] = fmaf(m, v.w, acc[c][3]);
            cnt[c]    = fmaf(m, cw, cnt[c]);
        }
    }
    #pragma unroll
    for (int c = 0; c < TYPE_N; ++c) {
        *reinterpret_cast<float4*>(&lsum[wid][c][lane * 4]) =
            make_float4(acc[c][0], acc[c][1], acc[c][2], acc[c][3]);
        if (lane == 0) lcnt[wid][c] = cnt[c];
    }
    __syncthreads();
    const int t = threadIdx.x;
    float* sums = ws + (size_t)(blockIdx.x % NCOPY) * (TYPE_N * D);
    #pragma unroll
    for (int c = 0; c < TYPE_N; ++c) {
        float s = lsum[0][c][t] + lsum[1][c][t] + lsum[2][c][t] + lsum[3][c][t];
        atomicAdd(&sums[c * D + t], s);
    }
    if (t < TYPE_N) {
        float s = lcnt[0][t] + lcnt[1][t] + lcnt[2][t] + lcnt[3][t];
        atomicAdd(&ws[OFF_CNTP + (blockIdx.x % NCOPY) * TYPE_N + t], s);
    }

    // ---- last-block-done: final block runs k2's body ----
    __threadfence();
    if (t == 0) {
        int prev = atomicAdd((int*)(ws + OFF_DONE), 1);
        is_last = (prev == (int)gridDim.x - 1) ? 1 : 0;
    }
    __syncthreads();
    if (is_last) {
        __threadfence();  // acquire: see all blocks' partials
        float cnts[TYPE_N];
        #pragma unroll
        for (int c = 0; c < TYPE_N; ++c) {
            float s = 0.f;
            #pragma unroll
            for (int p = 0; p < NCOPY; ++p) s += ws[OFF_CNTP + p * TYPE_N + c];
            cnts[c] = s;
        }
        float* center = ws + OFF_CENTER;
        float* cme    = ws + OFF_CME;
        #pragma unroll
        for (int c = 0; c < TYPE_N; ++c) {
            float s = 0.f;
            #pragma unroll
            for (int p = 0; p < NCOPY; ++p) s += ws[p * TYPE_N * D + c * D + t];
            float sc = fmaxf(cnts[c], 1.0f);
            float ctr = (cnts[c] > 0.f) ? s / sc : 0.f;
            center[c * D + t] = ctr;
            cme[c * D + t]    = ctr - EPS;
        }
        if (t < TYPE_N) ws[OFF_CNTF + t] = cnts[t];
    }
}

// --- K3 (+k4 in last block): distances -> final scalar -----------------------
// Loop body byte-identical to the measured ~38us R1/R6 k3. Do not touch.
__global__ __launch_bounds__(256) void k3_dist(const float* __restrict__ x,
                                               const float* __restrict__ y,
                                               float* __restrict__ ws,
                                               float* __restrict__ out, int N) {
    __shared__ float lds[4][TYPE_N];
    __shared__ int is_last;
    const int lane = threadIdx.x & 63;
    const int wid  = threadIdx.x >> 6;
    const int t = threadIdx.x;
    const int r = blockIdx.x * 256 + t;

    int lab = 0;
    float d = 0.f;
    if (r < N) {
        lab = argmax5(y + (size_t)r * TYPE_N);
        const float4* xr = reinterpret_cast<const float4*>(x + (size_t)r * D);
        const float4* cr = reinterpret_cast<const float4*>(ws + OFF_CME + lab * D);
        float ss[4] = {0.f, 0.f, 0.f, 0.f};
        #pragma unroll 8
        for (int i = 0; i < 64; ++i) {
            const float4 a = xr[i];
            const float4 b = cr[i];
            const float t0 = a.x - b.x;
            const float t1 = a.y - b.y;
            const float t2 = a.z - b.z;
            const float t3 = a.w - b.w;
            float s = fmaf(t0, t0, t1 * t1);
            s = fmaf(t2, t2, s);
            s = fmaf(t3, t3, s);
            ss[i & 3] += s;
        }
        d = sqrtf(ss[0] + ss[1] + ss[2] + ss[3]);
    }

    #pragma unroll
    for (int c = 0; c < TYPE_N; ++c) {
        float v = (lab == c) ? d : 0.f;
        #pragma unroll
        for (int off = 32; off > 0; off >>= 1) v += __shfl_xor(v, off);
        if (lane == 0) lds[wid][c] = v;
    }
    __syncthreads();
    if (t < TYPE_N) {
        float s = lds[0][t] + lds[1][t] + lds[2][t] + lds[3][t];
        atomicAdd(&ws[OFF_DSUM + (blockIdx.x % NCOPY) * TYPE_N + t], s);
    }

    // ---- last-block-done: final block runs k4's body (wave 0) ----
    __threadfence();
    if (t == 0) {
        int prev = atomicAdd((int*)(ws + OFF_DONE) + 1, 1);
        is_last = (prev == (int)gridDim.x - 1) ? 1 : 0;
    }
    __syncthreads();
    if (is_last && t < 64) {
        __threadfence();  // acquire
        const float* center = ws + OFF_CENTER;
        const float* counts = ws + OFF_CNTF;
        const float* dsp    = ws + OFF_DSUM;

        float csum[TYPE_N];
        #pragma unroll
        for (int c = 0; c < TYPE_N; ++c) {
            float s = 0.f;
            #pragma unroll
            for (int k = 0; k < 4; ++k) s += center[c * D + t * 4 + k];
            #pragma unroll
            for (int off = 32; off > 0; off >>= 1) s += __shfl_xor(s, off);
            csum[c] = s;
        }

        float cnts[TYPE_N], dsum[TYPE_N];
        bool present[TYPE_N];
        float real_n = 0.f;
        #pragma unroll
        for (int c = 0; c < TYPE_N; ++c) {
            cnts[c] = counts[c];
            float s = 0.f;
            #pragma unroll
            for (int p = 0; p < NCOPY; ++p) s += dsp[p * TYPE_N + c];
            dsum[c] = s;
            present[c] = (cnts[c] > 0.f) && (csum[c] != 0.f);
            real_n += present[c] ? 1.f : 0.f;
        }

        float loss_pos = 0.f;
        #pragma unroll
        for (int c = 0; c < TYPE_N; ++c) {
            float pcm = dsum[c] / fmaxf(cnts[c], 1.f);
            loss_pos += present[c] ? pcm : 0.f;
        }
        loss_pos = (real_n > 0.f) ? loss_pos / fmaxf(real_n, 1.f) : 1.0f;

        float pairsum = 0.f;
        #pragma unroll
        for (int i = 0; i < TYPE_N; ++i) {
            #pragma unroll
            for (int j = i + 1; j < TYPE_N; ++j) {
                float s = 0.f;
                #pragma unroll
                for (int k = 0; k < 4; ++k) {
                    float dd = center[i * D + t * 4 + k] - center[j * D + t * 4 + k] + EPS;
                    s += dd * dd;
                }
                #pragma unroll
                for (int off = 32; off > 0; off >>= 1) s += __shfl_xor(s, off);
                float pd = sqrtf(s);
                pairsum += (present[i] && present[j]) ? pd : 0.f;
            }
        }
        float n_pairs = real_n * (real_n - 1.f) * 0.5f;
        float loss_neg = (real_n > 1.f) ? pairsum / fmaxf(n_pairs, 1.f) : 0.f;

        if (t == 0) out[0] = loss_pos / (loss_neg + loss_pos);
    }
}

extern "C" void kernel_launch(void* const* d_in, const int* in_sizes, int n_in,
                              void* d_out, int out_size, void* d_ws, size_t ws_size,
                              hipStream_t stream) {
    const float* x = (const float*)d_in[0];
    const float* y = (const float*)d_in[1];
    float* out = (float*)d_out;
    float* ws  = (float*)d_ws;
    const int N = in_sizes[0] / D;  // 200000

    (void)hipMemsetAsync(d_ws, 0, (size_t)WS_FLOATS * sizeof(float), stream);

    k1_sums<<<2048, 256, 0, stream>>>(x, y, ws, N);
    const int grid3 = (N + 255) / 256;  // one row per thread
    k3_dist<<<grid3, 256, 0, stream>>>(x, y, ws, out, N);
}

// Round 11
// 245.728 us; speedup vs baseline: 2.9257x; 1.3895x over previous
//
#include <hip/hip_runtime.h>
#include <math.h>

#define TYPE_N 5
#define D 256
#define EPS 1e-6f
#define NCOPY 16

// ws layout (float offsets):
//   [0, 20480)        sums_partial[NCOPY][TYPE_N][D]
//   [20480, 20560)    counts_partial[NCOPY][TYPE_N]
//   [20560, 21840)    center[TYPE_N][D]          (raw)
//   [21840, 21845)    counts_final[TYPE_N]
//   [21845, 21925)    dsum_partial[NCOPY][TYPE_N]
//   [21925, 23205)    cme[TYPE_N][D]             (center - EPS)
//   [23205, 23207)    done counters (int): [0] unused, [1] k3
//   [23232, 43792)    PROBE scratch (k1n): sums[NCOPY][5][256] + cnts
#define OFF_CNTP   (NCOPY * TYPE_N * D)          // 20480
#define OFF_CENTER (OFF_CNTP + NCOPY * TYPE_N)   // 20560
#define OFF_CNTF   (OFF_CENTER + TYPE_N * D)     // 21840
#define OFF_DSUM   (OFF_CNTF + TYPE_N)           // 21845
#define OFF_CME    (OFF_DSUM + NCOPY * TYPE_N)   // 21925
#define OFF_DONE   (OFF_CME + TYPE_N * D)        // 23205
#define WS_FLOATS  (OFF_DONE + 2)                // 23207
#define PROBE_BASE   23232
#define PROBE_FLOATS (NCOPY * TYPE_N * D + NCOPY * TYPE_N)

__device__ __forceinline__ int argmax5(const float* __restrict__ yr) {
    int lab = 0;
    float best = yr[0];
    #pragma unroll
    for (int c = 1; c < TYPE_N; ++c) {
        float v = yr[c];
        if (v > best) { best = v; lab = c; }
    }
    return lab;
}

// serial lane-0 label + broadcast — part of the PROVEN-fast R0 k1 loop shape.
__device__ __forceinline__ int row_label(const float* __restrict__ y, int r, int lane) {
    int lab = 0;
    if (lane == 0) {
        const float* yr = y + (size_t)r * TYPE_N;
        float best = yr[0];
        #pragma unroll
        for (int c = 1; c < TYPE_N; ++c) {
            float v = yr[c];
            if (v > best) { best = v; lab = c; }
        }
    }
    return __shfl(lab, 0);
}

// --- K1: PRISTINE R0/R6 body (measured ~60us). NOTHING may be added here. ---
__global__ __launch_bounds__(256) void k1_sums(const float* __restrict__ x,
                                               const float* __restrict__ y,
                                               float* __restrict__ ws, int N) {
    __shared__ float lsum[4][TYPE_N][D];
    __shared__ float lcnt[4][TYPE_N];
    const int lane = threadIdx.x & 63;
    const int wid  = threadIdx.x >> 6;
    float acc[TYPE_N][4] = {};
    float cnt[TYPE_N] = {};
    const float cw = (lane == 0) ? 1.0f : 0.0f;
    const int stride = gridDim.x * 4;
    for (int r = blockIdx.x * 4 + wid; r < N; r += stride) {
        int lab = row_label(y, r, lane);
        const float4 v = *reinterpret_cast<const float4*>(x + (size_t)r * D + lane * 4);
        #pragma unroll
        for (int c = 0; c < TYPE_N; ++c) {
            float m = (lab == c) ? 1.0f : 0.0f;
            acc[c][0] = fmaf(m, v.x, acc[c][0]);
            acc[c][1] = fmaf(m, v.y, acc[c][1]);
            acc[c][2] = fmaf(m, v.z, acc[c][2]);
            acc[c][3] = fmaf(m, v.w, acc[c][3]);
            cnt[c]    = fmaf(m, cw, cnt[c]);
        }
    }
    #pragma unroll
    for (int c = 0; c < TYPE_N; ++c) {
        *reinterpret_cast<float4*>(&lsum[wid][c][lane * 4]) =
            make_float4(acc[c][0], acc[c][1], acc[c][2], acc[c][3]);
        if (lane == 0) lcnt[wid][c] = cnt[c];
    }
    __syncthreads();
    const int t = threadIdx.x;
    float* sums = ws + (size_t)(blockIdx.x % NCOPY) * (TYPE_N * D);
    #pragma unroll
    for (int c = 0; c < TYPE_N; ++c) {
        float s = lsum[0][c][t] + lsum[1][c][t] + lsum[2][c][t] + lsum[3][c][t];
        atomicAdd(&sums[c * D + t], s);
    }
    if (t < TYPE_N) {
        float s = lcnt[0][t] + lcnt[1][t] + lcnt[2][t] + lcnt[3][t];
        atomicAdd(&ws[OFF_CNTP + (blockIdx.x % NCOPY) * TYPE_N + t], s);
    }
}

// --- K2: reduce copies -> centers (raw + eps-folded) ------------------------
__global__ __launch_bounds__(256) void k2_center(float* __restrict__ ws) {
    const int t = threadIdx.x;  // column 0..255
    float cnts[TYPE_N];
    #pragma unroll
    for (int c = 0; c < TYPE_N; ++c) {
        float s = 0.f;
        #pragma unroll
        for (int p = 0; p < NCOPY; ++p) s += ws[OFF_CNTP + p * TYPE_N + c];
        cnts[c] = s;
    }
    float* center = ws + OFF_CENTER;
    float* cme    = ws + OFF_CME;
    #pragma unroll
    for (int c = 0; c < TYPE_N; ++c) {
        float s = 0.f;
        #pragma unroll
        for (int p = 0; p < NCOPY; ++p) s += ws[p * TYPE_N * D + c * D + t];
        float sc = fmaxf(cnts[c], 1.0f);
        float ctr = (cnts[c] > 0.f) ? s / sc : 0.f;
        center[c * D + t] = ctr;
        cme[c * D + t]    = ctr - EPS;
    }
    if (t < TYPE_N) ws[OFF_CNTF + t] = cnts[t];
}

// --- K3 (+k4 in last block): distances -> final scalar (proven ~40us R10) ---
__global__ __launch_bounds__(256) void k3_dist(const float* __restrict__ x,
                                               const float* __restrict__ y,
                                               float* __restrict__ ws,
                                               float* __restrict__ out, int N) {
    __shared__ float lds[4][TYPE_N];
    __shared__ int is_last;
    const int lane = threadIdx.x & 63;
    const int wid  = threadIdx.x >> 6;
    const int t = threadIdx.x;
    const int r = blockIdx.x * 256 + t;

    int lab = 0;
    float d = 0.f;
    if (r < N) {
        lab = argmax5(y + (size_t)r * TYPE_N);
        const float4* xr = reinterpret_cast<const float4*>(x + (size_t)r * D);
        const float4* cr = reinterpret_cast<const float4*>(ws + OFF_CME + lab * D);
        float ss[4] = {0.f, 0.f, 0.f, 0.f};
        #pragma unroll 8
        for (int i = 0; i < 64; ++i) {
            const float4 a = xr[i];
            const float4 b = cr[i];
            const float t0 = a.x - b.x;
            const float t1 = a.y - b.y;
            const float t2 = a.z - b.z;
            const float t3 = a.w - b.w;
            float s = fmaf(t0, t0, t1 * t1);
            s = fmaf(t2, t2, s);
            s = fmaf(t3, t3, s);
            ss[i & 3] += s;
        }
        d = sqrtf(ss[0] + ss[1] + ss[2] + ss[3]);
    }

    #pragma unroll
    for (int c = 0; c < TYPE_N; ++c) {
        float v = (lab == c) ? d : 0.f;
        #pragma unroll
        for (int off = 32; off > 0; off >>= 1) v += __shfl_xor(v, off);
        if (lane == 0) lds[wid][c] = v;
    }
    __syncthreads();
    if (t < TYPE_N) {
        float s = lds[0][t] + lds[1][t] + lds[2][t] + lds[3][t];
        atomicAdd(&ws[OFF_DSUM + (blockIdx.x % NCOPY) * TYPE_N + t], s);
    }

    __threadfence();
    if (t == 0) {
        int prev = atomicAdd((int*)(ws + OFF_DONE) + 1, 1);
        is_last = (prev == (int)gridDim.x - 1) ? 1 : 0;
    }
    __syncthreads();
    if (is_last && t < 64) {
        __threadfence();
        const float* center = ws + OFF_CENTER;
        const float* counts = ws + OFF_CNTF;
        const float* dsp    = ws + OFF_DSUM;

        float csum[TYPE_N];
        #pragma unroll
        for (int c = 0; c < TYPE_N; ++c) {
            float s = 0.f;
            #pragma unroll
            for (int k = 0; k < 4; ++k) s += center[c * D + t * 4 + k];
            #pragma unroll
            for (int off = 32; off > 0; off >>= 1) s += __shfl_xor(s, off);
            csum[c] = s;
        }

        float cnts[TYPE_N], dsum[TYPE_N];
        bool present[TYPE_N];
        float real_n = 0.f;
        #pragma unroll
        for (int c = 0; c < TYPE_N; ++c) {
            cnts[c] = counts[c];
            float s = 0.f;
            #pragma unroll
            for (int p = 0; p < NCOPY; ++p) s += dsp[p * TYPE_N + c];
            dsum[c] = s;
            present[c] = (cnts[c] > 0.f) && (csum[c] != 0.f);
            real_n += present[c] ? 1.f : 0.f;
        }

        float loss_pos = 0.f;
        #pragma unroll
        for (int c = 0; c < TYPE_N; ++c) {
            float pcm = dsum[c] / fmaxf(cnts[c], 1.f);
            loss_pos += present[c] ? pcm : 0.f;
        }
        loss_pos = (real_n > 0.f) ? loss_pos / fmaxf(real_n, 1.f) : 1.0f;

        float pairsum = 0.f;
        #pragma unroll
        for (int i = 0; i < TYPE_N; ++i) {
            #pragma unroll
            for (int j = i + 1; j < TYPE_N; ++j) {
                float s = 0.f;
                #pragma unroll
                for (int k = 0; k < 4; ++k) {
                    float dd = center[i * D + t * 4 + k] - center[j * D + t * 4 + k] + EPS;
                    s += dd * dd;
                }
                #pragma unroll
                for (int off = 32; off > 0; off >>= 1) s += __shfl_xor(s, off);
                float pd = sqrtf(s);
                pairsum += (present[i] && present[j]) ? pd : 0.f;
            }
        }
        float n_pairs = real_n * (real_n - 1.f) * 0.5f;
        float loss_neg = (real_n > 1.f) ? pairsum / fmaxf(n_pairs, 1.f) : 0.f;

        if (t == 0) out[0] = loss_pos / (loss_neg + loss_pos);
    }
}

// --- K1N PROBE: candidate k1 replacement, writes to scratch only. ----------
// Block owns 100 rows; per iteration 4 rows: y-addresses are BLOCK-UNIFORM
// (scalarizable, hoistable), thread = (row-in-4 = tid>>6, 16B col = lane).
__global__ __launch_bounds__(256) void k1n_probe(const float* __restrict__ x,
                                                 const float* __restrict__ y,
                                                 float* __restrict__ wsp, int N) {
    __shared__ float lsum[4][TYPE_N][D];
    __shared__ float lcnt[4][TYPE_N];
    const int lane = threadIdx.x & 63;
    const int sub  = threadIdx.x >> 6;
    const int r0   = blockIdx.x * 100;
    const int rows = (N - r0 < 100) ? (N - r0) : 100;

    float acc[TYPE_N][4] = {};
    float cnt[TYPE_N] = {};
    const float cw = (lane == 0) ? 1.0f : 0.0f;

    const int ng = rows >> 2;
    for (int i = 0; i < ng; ++i) {
        const int rb = r0 + i * 4;
        const int lab0 = argmax5(y + (size_t)rb * TYPE_N);        // uniform addr
        const int lab1 = argmax5(y + (size_t)(rb + 1) * TYPE_N);  // uniform addr
        const int lab2 = argmax5(y + (size_t)(rb + 2) * TYPE_N);  // uniform addr
        const int lab3 = argmax5(y + (size_t)(rb + 3) * TYPE_N);  // uniform addr
        int lab = lab0;
        lab = (sub == 1) ? lab1 : lab;
        lab = (sub == 2) ? lab2 : lab;
        lab = (sub == 3) ? lab3 : lab;
        const float4 v = *reinterpret_cast<const float4*>(
            x + (size_t)(rb + sub) * D + lane * 4);
        #pragma unroll
        for (int c = 0; c < TYPE_N; ++c) {
            const float m = (lab == c) ? 1.0f : 0.0f;
            acc[c][0] = fmaf(m, v.x, acc[c][0]);
            acc[c][1] = fmaf(m, v.y, acc[c][1]);
            acc[c][2] = fmaf(m, v.z, acc[c][2]);
            acc[c][3] = fmaf(m, v.w, acc[c][3]);
            cnt[c]    = fmaf(m, cw, cnt[c]);
        }
    }
    for (int r = r0 + (ng << 2) + sub; r < r0 + rows; r += 4) {  // tail (<4 rows)
        const int lab = argmax5(y + (size_t)r * TYPE_N);
        const float4 v = *reinterpret_cast<const float4*>(
            x + (size_t)r * D + lane * 4);
        #pragma unroll
        for (int c = 0; c < TYPE_N; ++c) {
            const float m = (lab == c) ? 1.0f : 0.0f;
            acc[c][0] = fmaf(m, v.x, acc[c][0]);
            acc[c][1] = fmaf(m, v.y, acc[c][1]);
            acc[c][2] = fmaf(m, v.z, acc[c][2]);
            acc[c][3] = fmaf(m, v.w, acc[c][3]);
            cnt[c]    = fmaf(m, cw, cnt[c]);
        }
    }

    #pragma unroll
    for (int c = 0; c < TYPE_N; ++c) {
        *reinterpret_cast<float4*>(&lsum[sub][c][lane * 4]) =
            make_float4(acc[c][0], acc[c][1], acc[c][2], acc[c][3]);
        if (lane == 0) lcnt[sub][c] = cnt[c];
    }
    __syncthreads();
    const int t = threadIdx.x;
    float* sums = wsp + (size_t)(blockIdx.x % NCOPY) * (TYPE_N * D);
    #pragma unroll
    for (int c = 0; c < TYPE_N; ++c) {
        float s = lsum[0][c][t] + lsum[1][c][t] + lsum[2][c][t] + lsum[3][c][t];
        atomicAdd(&sums[c * D + t], s);
    }
    if (t < TYPE_N) {
        float s = lcnt[0][t] + lcnt[1][t] + lcnt[2][t] + lcnt[3][t];
        atomicAdd(&wsp[NCOPY * TYPE_N * D + t], s);
    }
}

extern "C" void kernel_launch(void* const* d_in, const int* in_sizes, int n_in,
                              void* d_out, int out_size, void* d_ws, size_t ws_size,
                              hipStream_t stream) {
    const float* x = (const float*)d_in[0];
    const float* y = (const float*)d_in[1];
    float* out = (float*)d_out;
    float* ws  = (float*)d_ws;
    const int N = in_sizes[0] / D;  // 200000

    (void)hipMemsetAsync(d_ws, 0, (size_t)WS_FLOATS * sizeof(float), stream);

    k1_sums<<<2048, 256, 0, stream>>>(x, y, ws, N);
    k2_center<<<1, 256, 0, stream>>>(ws);
    const int grid3 = (N + 255) / 256;
    k3_dist<<<grid3, 256, 0, stream>>>(x, y, ws, out, N);

    // A/B probe: candidate k1 replacement into scratch (after out is written).
    if (ws_size >= (size_t)(PROBE_BASE + PROBE_FLOATS) * sizeof(float)) {
        const int gridP = (N + 99) / 100;
        k1n_probe<<<gridP, 256, 0, stream>>>(x, y, ws + PROBE_BASE, N);
    }
}

// Round 12
// 115.239 us; speedup vs baseline: 6.2386x; 2.1323x over previous
//
#include <hip/hip_runtime.h>
#include <math.h>

#define TYPE_N 5
#define D 256
#define EPS 1e-6f
#define NCOPY 16
#define RPB 100   // rows per block in k1 (block-uniform label scheme)

// ws layout (float offsets):
//   [0, 20480)        sums_partial[NCOPY][TYPE_N][D]
//   [20480, 20560)    counts_partial[NCOPY][TYPE_N]
//   [20560, 21840)    center[TYPE_N][D]          (raw)
//   [21840, 21845)    counts_final[TYPE_N]
//   [21845, 21925)    dsum_partial[NCOPY][TYPE_N]
//   [21925, 23205)    cme[TYPE_N][D]             (center - EPS)
#define OFF_CNTP   (NCOPY * TYPE_N * D)          // 20480
#define OFF_CENTER (OFF_CNTP + NCOPY * TYPE_N)   // 20560
#define OFF_CNTF   (OFF_CENTER + TYPE_N * D)     // 21840
#define OFF_DSUM   (OFF_CNTF + TYPE_N)           // 21845
#define OFF_CME    (OFF_DSUM + NCOPY * TYPE_N)   // 21925
#define WS_FLOATS  (OFF_CME + TYPE_N * D)        // 23205

__device__ __forceinline__ int argmax5(const float* __restrict__ yr) {
    int lab = 0;
    float best = yr[0];
    #pragma unroll
    for (int c = 1; c < TYPE_N; ++c) {
        float v = yr[c];
        if (v > best) { best = v; lab = c; }
    }
    return lab;
}

// --- K1: counts + centroid column sums (k1n structure, A/B-proven R10) ------
// Block owns RPB contiguous rows; per iteration 4 rows. The 4 labels are
// computed from BLOCK-UNIFORM y-addresses (scalarized by the compiler, off
// the per-lane critical path). Wave `sub` streams row rb+sub with a
// coalesced float4 load. NO tail code — streaming kernels stay pristine.
__global__ __launch_bounds__(256) void k1_sums(const float* __restrict__ x,
                                               const float* __restrict__ y,
                                               float* __restrict__ ws, int N) {
    __shared__ float lsum[4][TYPE_N][D];
    __shared__ float lcnt[4][TYPE_N];
    const int lane = threadIdx.x & 63;
    const int sub  = threadIdx.x >> 6;
    const int r0   = blockIdx.x * RPB;
    const int rows = (N - r0 < RPB) ? (N - r0) : RPB;

    float acc[TYPE_N][4] = {};
    float cnt[TYPE_N] = {};
    const float cw = (lane == 0) ? 1.0f : 0.0f;  // lane0 of each wave counts its rows

    const int ng = rows >> 2;
    for (int i = 0; i < ng; ++i) {
        const int rb = r0 + i * 4;
        const int lab0 = argmax5(y + (size_t)rb * TYPE_N);        // uniform addr
        const int lab1 = argmax5(y + (size_t)(rb + 1) * TYPE_N);  // uniform addr
        const int lab2 = argmax5(y + (size_t)(rb + 2) * TYPE_N);  // uniform addr
        const int lab3 = argmax5(y + (size_t)(rb + 3) * TYPE_N);  // uniform addr
        int lab = lab0;
        lab = (sub == 1) ? lab1 : lab;
        lab = (sub == 2) ? lab2 : lab;
        lab = (sub == 3) ? lab3 : lab;
        const float4 v = *reinterpret_cast<const float4*>(
            x + (size_t)(rb + sub) * D + lane * 4);
        #pragma unroll
        for (int c = 0; c < TYPE_N; ++c) {
            const float m = (lab == c) ? 1.0f : 0.0f;
            acc[c][0] = fmaf(m, v.x, acc[c][0]);
            acc[c][1] = fmaf(m, v.y, acc[c][1]);
            acc[c][2] = fmaf(m, v.z, acc[c][2]);
            acc[c][3] = fmaf(m, v.w, acc[c][3]);
            cnt[c]    = fmaf(m, cw, cnt[c]);
        }
    }
    for (int r = r0 + (ng << 2) + sub; r < r0 + rows; r += 4) {  // tail rows (<4)
        const int lab = argmax5(y + (size_t)r * TYPE_N);
        const float4 v = *reinterpret_cast<const float4*>(
            x + (size_t)r * D + lane * 4);
        #pragma unroll
        for (int c = 0; c < TYPE_N; ++c) {
            const float m = (lab == c) ? 1.0f : 0.0f;
            acc[c][0] = fmaf(m, v.x, acc[c][0]);
            acc[c][1] = fmaf(m, v.y, acc[c][1]);
            acc[c][2] = fmaf(m, v.z, acc[c][2]);
            acc[c][3] = fmaf(m, v.w, acc[c][3]);
            cnt[c]    = fmaf(m, cw, cnt[c]);
        }
    }

    #pragma unroll
    for (int c = 0; c < TYPE_N; ++c) {
        *reinterpret_cast<float4*>(&lsum[sub][c][lane * 4]) =
            make_float4(acc[c][0], acc[c][1], acc[c][2], acc[c][3]);
        if (lane == 0) lcnt[sub][c] = cnt[c];
    }
    __syncthreads();
    const int t = threadIdx.x;
    float* sums = ws + (size_t)(blockIdx.x % NCOPY) * (TYPE_N * D);
    #pragma unroll
    for (int c = 0; c < TYPE_N; ++c) {
        float s = lsum[0][c][t] + lsum[1][c][t] + lsum[2][c][t] + lsum[3][c][t];
        atomicAdd(&sums[c * D + t], s);
    }
    if (t < TYPE_N) {
        float s = lcnt[0][t] + lcnt[1][t] + lcnt[2][t] + lcnt[3][t];
        atomicAdd(&ws[OFF_CNTP + (blockIdx.x % NCOPY) * TYPE_N + t], s);
    }
}

// --- K2: reduce copies -> centers (raw + eps-folded) ------------------------
__global__ __launch_bounds__(256) void k2_center(float* __restrict__ ws) {
    const int t = threadIdx.x;  // column 0..255
    float cnts[TYPE_N];
    #pragma unroll
    for (int c = 0; c < TYPE_N; ++c) {
        float s = 0.f;
        #pragma unroll
        for (int p = 0; p < NCOPY; ++p) s += ws[OFF_CNTP + p * TYPE_N + c];
        cnts[c] = s;
    }
    float* center = ws + OFF_CENTER;
    float* cme    = ws + OFF_CME;
    #pragma unroll
    for (int c = 0; c < TYPE_N; ++c) {
        float s = 0.f;
        #pragma unroll
        for (int p = 0; p < NCOPY; ++p) s += ws[p * TYPE_N * D + c * D + t];
        float sc = fmaxf(cnts[c], 1.0f);
        float ctr = (cnts[c] > 0.f) ? s / sc : 0.f;
        center[c * D + t] = ctr;
        cme[c * D + t]    = ctr - EPS;
    }
    if (t < TYPE_N) ws[OFF_CNTF + t] = cnts[t];
}

// --- K3: row-per-thread distances (R6-exact, NO tail) -----------------------
__global__ __launch_bounds__(256) void k3_dist(const float* __restrict__ x,
                                               const float* __restrict__ y,
                                               float* __restrict__ ws, int N) {
    __shared__ float lds[4][TYPE_N];
    const int lane = threadIdx.x & 63;
    const int wid  = threadIdx.x >> 6;
    const int r = blockIdx.x * 256 + threadIdx.x;

    int lab = 0;
    float d = 0.f;
    if (r < N) {
        lab = argmax5(y + (size_t)r * TYPE_N);
        const float4* xr = reinterpret_cast<const float4*>(x + (size_t)r * D);
        const float4* cr = reinterpret_cast<const float4*>(ws + OFF_CME + lab * D);
        float ss[4] = {0.f, 0.f, 0.f, 0.f};
        #pragma unroll 8
        for (int i = 0; i < 64; ++i) {
            const float4 a = xr[i];
            const float4 b = cr[i];
            const float t0 = a.x - b.x;
            const float t1 = a.y - b.y;
            const float t2 = a.z - b.z;
            const float t3 = a.w - b.w;
            float s = fmaf(t0, t0, t1 * t1);
            s = fmaf(t2, t2, s);
            s = fmaf(t3, t3, s);
            ss[i & 3] += s;
        }
        d = sqrtf(ss[0] + ss[1] + ss[2] + ss[3]);
    }

    #pragma unroll
    for (int c = 0; c < TYPE_N; ++c) {
        float v = (lab == c) ? d : 0.f;
        #pragma unroll
        for (int off = 32; off > 0; off >>= 1) v += __shfl_xor(v, off);
        if (lane == 0) lds[wid][c] = v;
    }
    __syncthreads();
    if (threadIdx.x < TYPE_N) {
        float s = lds[0][threadIdx.x] + lds[1][threadIdx.x] +
                  lds[2][threadIdx.x] + lds[3][threadIdx.x];
        atomicAdd(&ws[OFF_DSUM + (blockIdx.x % NCOPY) * TYPE_N + threadIdx.x], s);
    }
}

// --- K4: scalar epilogue -----------------------------------------------------
__global__ __launch_bounds__(64) void k4_final(const float* __restrict__ ws,
                                               float* __restrict__ out) {
    const int lane = threadIdx.x;  // 0..63
    const float* center = ws + OFF_CENTER;
    const float* counts = ws + OFF_CNTF;
    const float* dsp    = ws + OFF_DSUM;

    float csum[TYPE_N];
    #pragma unroll
    for (int c = 0; c < TYPE_N; ++c) {
        float s = 0.f;
        #pragma unroll
        for (int k = 0; k < 4; ++k) s += center[c * D + lane * 4 + k];
        #pragma unroll
        for (int off = 32; off > 0; off >>= 1) s += __shfl_xor(s, off);
        csum[c] = s;
    }

    float cnts[TYPE_N], dsum[TYPE_N];
    bool present[TYPE_N];
    float real_n = 0.f;
    #pragma unroll
    for (int c = 0; c < TYPE_N; ++c) {
        cnts[c] = counts[c];
        float s = 0.f;
        #pragma unroll
        for (int p = 0; p < NCOPY; ++p) s += dsp[p * TYPE_N + c];
        dsum[c] = s;
        present[c] = (cnts[c] > 0.f) && (csum[c] != 0.f);
        real_n += present[c] ? 1.f : 0.f;
    }

    float loss_pos = 0.f;
    #pragma unroll
    for (int c = 0; c < TYPE_N; ++c) {
        float pcm = dsum[c] / fmaxf(cnts[c], 1.f);
        loss_pos += present[c] ? pcm : 0.f;
    }
    loss_pos = (real_n > 0.f) ? loss_pos / fmaxf(real_n, 1.f) : 1.0f;

    float pairsum = 0.f;
    #pragma unroll
    for (int i = 0; i < TYPE_N; ++i) {
        #pragma unroll
        for (int j = i + 1; j < TYPE_N; ++j) {
            float s = 0.f;
            #pragma unroll
            for (int k = 0; k < 4; ++k) {
                float dd = center[i * D + lane * 4 + k] - center[j * D + lane * 4 + k] + EPS;
                s += dd * dd;
            }
            #pragma unroll
            for (int off = 32; off > 0; off >>= 1) s += __shfl_xor(s, off);
            float pd = sqrtf(s);
            pairsum += (present[i] && present[j]) ? pd : 0.f;
        }
    }
    float n_pairs = real_n * (real_n - 1.f) * 0.5f;
    float loss_neg = (real_n > 1.f) ? pairsum / fmaxf(n_pairs, 1.f) : 0.f;

    if (lane == 0) out[0] = loss_pos / (loss_neg + loss_pos);
}

extern "C" void kernel_launch(void* const* d_in, const int* in_sizes, int n_in,
                              void* d_out, int out_size, void* d_ws, size_t ws_size,
                              hipStream_t stream) {
    const float* x = (const float*)d_in[0];
    const float* y = (const float*)d_in[1];
    float* out = (float*)d_out;
    float* ws  = (float*)d_ws;
    const int N = in_sizes[0] / D;  // 200000

    (void)hipMemsetAsync(d_ws, 0, (size_t)WS_FLOATS * sizeof(float), stream);

    const int grid1 = (N + RPB - 1) / RPB;   // 2000 blocks, 100 rows each
    k1_sums<<<grid1, 256, 0, stream>>>(x, y, ws, N);
    k2_center<<<1, 256, 0, stream>>>(ws);
    const int grid3 = (N + 255) / 256;       // one row per thread
    k3_dist<<<grid3, 256, 0, stream>>>(x, y, ws, N);
    k4_final<<<1, 64, 0, stream>>>(ws, out);
}